// Round 1
// baseline (421.612 us; speedup 1.0000x reference)
//
#include <hip/hip_runtime.h>

#define NF 128   // feature dim, fixed by the problem

// ---------------- CSR build ----------------

__global__ void zero_int(int* __restrict__ p, int n) {
    int i = blockIdx.x * 256 + threadIdx.x;
    if (i < n) p[i] = 0;
}

__global__ void count_k(const int* __restrict__ dst, int* __restrict__ cnt, int E, int N) {
    int e = blockIdx.x * 256 + threadIdx.x;
    if (e < E) {
        int d = dst[e];
        if ((unsigned)d < (unsigned)N) atomicAdd(&cnt[d], 1);
    }
}

__global__ void dinv_k(const int* __restrict__ cnt, float* __restrict__ dinv, int n) {
    int i = blockIdx.x * 256 + threadIdx.x;
    if (i < n) dinv[i] = rsqrtf((float)cnt[i] + 1.0f);  // +1 = self-loop
}

// single-block two-level exclusive scan of cnt[0..n) -> rowptr[0..n]
__global__ __launch_bounds__(1024) void scan_k(const int* __restrict__ cnt,
                                               int* __restrict__ rowptr, int n) {
    __shared__ int sm[1024];
    int tid = threadIdx.x;
    int chunk = (n + 1023) >> 10;
    int s = tid * chunk;
    int e = min(s + chunk, n);
    int sum = 0;
    for (int i = s; i < e; i++) sum += cnt[i];
    sm[tid] = sum;
    __syncthreads();
    for (int d = 1; d < 1024; d <<= 1) {
        int t = (tid >= d) ? sm[tid - d] : 0;
        __syncthreads();
        sm[tid] += t;
        __syncthreads();
    }
    int off = sm[tid] - sum;   // exclusive prefix
    for (int i = s; i < e; i++) { rowptr[i] = off; off += cnt[i]; }
    if (tid == 1023) rowptr[n] = off;  // == E
}

__global__ void initcur_k(const int* __restrict__ rowptr, int* __restrict__ cur, int n) {
    int i = blockIdx.x * 256 + threadIdx.x;
    if (i < n) cur[i] = rowptr[i];
}

__global__ void fill_k(const int* __restrict__ src, const int* __restrict__ dst,
                       int* __restrict__ cur, int* __restrict__ csr, int E, int N) {
    int e = blockIdx.x * 256 + threadIdx.x;
    if (e < E) {
        int d = dst[e];
        if ((unsigned)d < (unsigned)N) {
            int p = atomicAdd(&cur[d], 1);
            csr[p] = src[e];
        }
    }
}

// ---------------- GEMM: out[i][j] = dinv[i] * sum_k X[i][k] W[k][j] ----------------
// M x 128 @ 128 x 128, fp32 vector ALU. Tile 32 rows x 64 cols, 256 threads,
// thread micro-tile 2x4. xs padded to stride 132 -> conflict-free a-reads.

__global__ __launch_bounds__(256) void gemm_scaled(
    const float* __restrict__ X, const float* __restrict__ W,
    const float* __restrict__ dinv, float* __restrict__ out, int M)
{
    __shared__ float xs[32][132];    // 16.9 KB
    __shared__ float ws[128][64];    // 32 KB
    const int tid  = threadIdx.x;
    const int row0 = blockIdx.x * 32;
    const int col0 = blockIdx.y * 64;

    {   // load x tile (guarded rows)
        int r = tid >> 5, c4 = (tid & 31) * 4;
        #pragma unroll
        for (int rr = r; rr < 32; rr += 8) {
            int grow = row0 + rr;
            float4 v = make_float4(0.f, 0.f, 0.f, 0.f);
            if (grow < M) v = *(const float4*)(X + (size_t)grow * NF + c4);
            *(float4*)&xs[rr][c4] = v;   // 528 B row pitch: 16B-aligned
        }
    }
    {   // load W half-tile (cols col0..col0+63)
        int r = tid >> 4, c4 = (tid & 15) * 4;
        #pragma unroll
        for (int rr = r; rr < 128; rr += 16) {
            float4 v = *(const float4*)(W + (size_t)rr * NF + col0 + c4);
            *(float4*)&ws[rr][c4] = v;
        }
    }
    __syncthreads();

    const int r0 = (tid >> 4) * 2;
    const int c0 = (tid & 15) * 4;
    float acc00 = 0, acc01 = 0, acc02 = 0, acc03 = 0;
    float acc10 = 0, acc11 = 0, acc12 = 0, acc13 = 0;
    #pragma unroll 8
    for (int k = 0; k < 128; k++) {
        float a0 = xs[r0][k], a1 = xs[r0 + 1][k];
        float4 b = *(const float4*)&ws[k][c0];
        acc00 += a0 * b.x; acc01 += a0 * b.y; acc02 += a0 * b.z; acc03 += a0 * b.w;
        acc10 += a1 * b.x; acc11 += a1 * b.y; acc12 += a1 * b.z; acc13 += a1 * b.w;
    }
    int g0 = row0 + r0;
    if (g0 < M) {
        float s = dinv[g0];
        *(float4*)(out + (size_t)g0 * NF + col0 + c0) =
            make_float4(acc00 * s, acc01 * s, acc02 * s, acc03 * s);
    }
    int g1 = g0 + 1;
    if (g1 < M) {
        float s = dinv[g1];
        *(float4*)(out + (size_t)g1 * NF + col0 + c0) =
            make_float4(acc10 * s, acc11 * s, acc12 * s, acc13 * s);
    }
}

// ---------------- Aggregation: one wave per node ----------------
// acc = hs[node] (self-loop) + sum over in-edges hs[src];
// out = dinv[node]*acc + bias  (optional relu). Lane holds float2 (128 feats / 64 lanes).

__global__ __launch_bounds__(256) void agg_k(
    const float* __restrict__ hs, const int* __restrict__ rowptr,
    const int* __restrict__ csr, const float* __restrict__ dinv,
    const float* __restrict__ bias, float* __restrict__ out,
    int n, int do_relu)
{
    int wave = threadIdx.x >> 6;
    int lane = threadIdx.x & 63;
    int node = blockIdx.x * 4 + wave;
    if (node >= n) return;

    const float2* self = (const float2*)(hs + (size_t)node * NF);
    float2 acc = self[lane];

    int base = rowptr[node];
    int cnt  = rowptr[node + 1] - base;

    for (int off = 0; off < cnt; off += 64) {
        int m = min(64, cnt - off);
        int idx = 0;
        if (lane < m) idx = csr[base + off + lane];
        int j = 0;
        for (; j + 3 < m; j += 4) {   // 4 gathers in flight
            int s0 = __shfl(idx, j, 64);
            int s1 = __shfl(idx, j + 1, 64);
            int s2 = __shfl(idx, j + 2, 64);
            int s3 = __shfl(idx, j + 3, 64);
            float2 v0 = ((const float2*)(hs + (size_t)s0 * NF))[lane];
            float2 v1 = ((const float2*)(hs + (size_t)s1 * NF))[lane];
            float2 v2 = ((const float2*)(hs + (size_t)s2 * NF))[lane];
            float2 v3 = ((const float2*)(hs + (size_t)s3 * NF))[lane];
            acc.x += v0.x + v1.x + v2.x + v3.x;
            acc.y += v0.y + v1.y + v2.y + v3.y;
        }
        for (; j < m; j++) {
            int s0 = __shfl(idx, j, 64);
            float2 v0 = ((const float2*)(hs + (size_t)s0 * NF))[lane];
            acc.x += v0.x; acc.y += v0.y;
        }
    }

    float s = dinv[node];
    float ox = s * acc.x + bias[2 * lane];
    float oy = s * acc.y + bias[2 * lane + 1];
    if (do_relu) { ox = fmaxf(ox, 0.f); oy = fmaxf(oy, 0.f); }
    ((float2*)(out + (size_t)node * NF))[lane] = make_float2(ox, oy);
}

// ---------------- launch ----------------

extern "C" void kernel_launch(void* const* d_in, const int* in_sizes, int n_in,
                              void* d_out, int out_size, void* d_ws, size_t ws_size,
                              hipStream_t stream) {
    const float* x  = (const float*)d_in[0];
    const int*   ei = (const int*)d_in[1];   // harness delivers integer inputs as int32
    const float* W1 = (const float*)d_in[2];
    const float* b1 = (const float*)d_in[3];
    const float* W2 = (const float*)d_in[4];
    const float* b2 = (const float*)d_in[5];
    float* out = (float*)d_out;

    const int N = in_sizes[0] / NF;   // 50000
    const int E = in_sizes[1] / 2;    // 800000
    const int* src = ei;
    const int* dst = ei + E;

    char* ws = (char*)d_ws;
    size_t off = 0;
    auto alloc = [&](size_t bytes) {
        void* p = ws + off;
        off += bytes;
        off = (off + 63) & ~(size_t)63;
        return p;
    };
    int*   cnt    = (int*)alloc((size_t)N * 4);        // reused as fill cursor
    int*   rowptr = (int*)alloc((size_t)(N + 1) * 4);
    int*   csr    = (int*)alloc((size_t)E * 4);
    float* dinv   = (float*)alloc((size_t)N * 4);
    float* H      = (float*)alloc((size_t)N * NF * 4);
    float* A      = (float*)alloc((size_t)N * NF * 4);

    int nb = (N + 255) / 256;
    int eb = (E + 255) / 256;

    zero_int<<<nb, 256, 0, stream>>>(cnt, N);
    count_k<<<eb, 256, 0, stream>>>(dst, cnt, E, N);
    dinv_k<<<nb, 256, 0, stream>>>(cnt, dinv, N);
    scan_k<<<1, 1024, 0, stream>>>(cnt, rowptr, N);
    initcur_k<<<nb, 256, 0, stream>>>(rowptr, cnt, N);
    fill_k<<<eb, 256, 0, stream>>>(src, dst, cnt, csr, E, N);

    dim3 gg((N + 31) / 32, 2);
    gemm_scaled<<<gg, 256, 0, stream>>>(x, W1, dinv, H, N);
    int ab = (N + 3) / 4;
    agg_k<<<ab, 256, 0, stream>>>(H, rowptr, csr, dinv, b1, A, N, 1);
    gemm_scaled<<<gg, 256, 0, stream>>>(A, W2, dinv, H, N);
    agg_k<<<ab, 256, 0, stream>>>(H, rowptr, csr, dinv, b2, out, N, 0);
}

// Round 2
// 358.040 us; speedup vs baseline: 1.1776x; 1.1776x over previous
//
#include <hip/hip_runtime.h>

#define NF 128   // feature dim, fixed by the problem

// ---------------- CSR build ----------------

__global__ void zero_int(int* __restrict__ p, int n) {
    int i = blockIdx.x * 256 + threadIdx.x;
    if (i < n) p[i] = 0;
}

__global__ void count_k(const int* __restrict__ dst, int* __restrict__ cnt, int E, int N) {
    int e = blockIdx.x * 256 + threadIdx.x;
    if (e < E) {
        int d = dst[e];
        if ((unsigned)d < (unsigned)N) atomicAdd(&cnt[d], 1);
    }
}

// Phase 1: per-256-chunk local exclusive scan (into rowptr) + block totals.
// Also computes dinv = rsqrt(deg+1) since cnt is already in hand.
__global__ __launch_bounds__(256) void pscan_local(
    const int* __restrict__ cnt, float* __restrict__ dinv,
    int* __restrict__ rowptr, int* __restrict__ blocksum, int n)
{
    __shared__ int sm[256];
    int tid = threadIdx.x;
    int i = blockIdx.x * 256 + tid;
    int v = (i < n) ? cnt[i] : 0;
    if (i < n) dinv[i] = rsqrtf((float)v + 1.0f);  // +1 = self-loop
    sm[tid] = v;
    __syncthreads();
    #pragma unroll
    for (int d = 1; d < 256; d <<= 1) {
        int t = (tid >= d) ? sm[tid - d] : 0;
        __syncthreads();
        sm[tid] += t;
        __syncthreads();
    }
    if (i < n) rowptr[i] = sm[tid] - v;            // local exclusive prefix
    if (tid == 255) blocksum[blockIdx.x] = sm[255];
}

// Phase 2: single-block exclusive scan of the block sums (nb <= 256).
__global__ __launch_bounds__(256) void scan_blk(int* __restrict__ blocksum, int nb) {
    __shared__ int sm[256];
    int tid = threadIdx.x;
    int v = (tid < nb) ? blocksum[tid] : 0;
    sm[tid] = v;
    __syncthreads();
    #pragma unroll
    for (int d = 1; d < 256; d <<= 1) {
        int t = (tid >= d) ? sm[tid - d] : 0;
        __syncthreads();
        sm[tid] += t;
        __syncthreads();
    }
    if (tid < nb) blocksum[tid] = sm[tid] - v;     // exclusive block offsets
}

// Phase 3: add block offsets; also init the fill cursor and rowptr[n].
__global__ __launch_bounds__(256) void add_off(
    int* __restrict__ rowptr, int* __restrict__ cur,
    const int* __restrict__ blocksum, int n, int E)
{
    int i = blockIdx.x * 256 + threadIdx.x;
    if (i < n) {
        int r = rowptr[i] + blocksum[blockIdx.x];
        rowptr[i] = r;
        cur[i] = r;
    }
    if (i == 0) rowptr[n] = E;   // all dst are in-range by construction
}

__global__ void fill_k(const int* __restrict__ src, const int* __restrict__ dst,
                       int* __restrict__ cur, int* __restrict__ csr, int E, int N) {
    int e = blockIdx.x * 256 + threadIdx.x;
    if (e < E) {
        int d = dst[e];
        if ((unsigned)d < (unsigned)N) {
            int p = atomicAdd(&cur[d], 1);
            csr[p] = src[e];
        }
    }
}

// ---------------- GEMM: out[i][j] = dinv[i] * sum_k X[i][k] W[k][j] ----------------
// M x 128 @ 128 x 128, fp32 vector ALU. Tile 32 rows x 64 cols, 256 threads,
// thread micro-tile 2x4. xs padded to stride 132 -> conflict-free a-reads.

__global__ __launch_bounds__(256) void gemm_scaled(
    const float* __restrict__ X, const float* __restrict__ W,
    const float* __restrict__ dinv, float* __restrict__ out, int M)
{
    __shared__ float xs[32][132];    // 16.9 KB
    __shared__ float ws[128][64];    // 32 KB
    const int tid  = threadIdx.x;
    const int row0 = blockIdx.x * 32;
    const int col0 = blockIdx.y * 64;

    {   // load x tile (guarded rows)
        int r = tid >> 5, c4 = (tid & 31) * 4;
        #pragma unroll
        for (int rr = r; rr < 32; rr += 8) {
            int grow = row0 + rr;
            float4 v = make_float4(0.f, 0.f, 0.f, 0.f);
            if (grow < M) v = *(const float4*)(X + (size_t)grow * NF + c4);
            *(float4*)&xs[rr][c4] = v;
        }
    }
    {   // load W half-tile (cols col0..col0+63)
        int r = tid >> 4, c4 = (tid & 15) * 4;
        #pragma unroll
        for (int rr = r; rr < 128; rr += 16) {
            float4 v = *(const float4*)(W + (size_t)rr * NF + col0 + c4);
            *(float4*)&ws[rr][c4] = v;
        }
    }
    __syncthreads();

    const int r0 = (tid >> 4) * 2;
    const int c0 = (tid & 15) * 4;
    float acc00 = 0, acc01 = 0, acc02 = 0, acc03 = 0;
    float acc10 = 0, acc11 = 0, acc12 = 0, acc13 = 0;
    #pragma unroll 8
    for (int k = 0; k < 128; k++) {
        float a0 = xs[r0][k], a1 = xs[r0 + 1][k];
        float4 b = *(const float4*)&ws[k][c0];
        acc00 += a0 * b.x; acc01 += a0 * b.y; acc02 += a0 * b.z; acc03 += a0 * b.w;
        acc10 += a1 * b.x; acc11 += a1 * b.y; acc12 += a1 * b.z; acc13 += a1 * b.w;
    }
    int g0 = row0 + r0;
    if (g0 < M) {
        float s = dinv[g0];
        *(float4*)(out + (size_t)g0 * NF + col0 + c0) =
            make_float4(acc00 * s, acc01 * s, acc02 * s, acc03 * s);
    }
    int g1 = g0 + 1;
    if (g1 < M) {
        float s = dinv[g1];
        *(float4*)(out + (size_t)g1 * NF + col0 + c0) =
            make_float4(acc10 * s, acc11 * s, acc12 * s, acc13 * s);
    }
}

// ---------------- Aggregation: one wave per node ----------------
// acc = hs[node] (self-loop) + sum over in-edges hs[src];
// out = dinv[node]*acc + bias  (optional relu). Lane holds float2 (128 feats / 64 lanes).

__global__ __launch_bounds__(256) void agg_k(
    const float* __restrict__ hs, const int* __restrict__ rowptr,
    const int* __restrict__ csr, const float* __restrict__ dinv,
    const float* __restrict__ bias, float* __restrict__ out,
    int n, int do_relu)
{
    int wave = threadIdx.x >> 6;
    int lane = threadIdx.x & 63;
    int node = blockIdx.x * 4 + wave;
    if (node >= n) return;

    const float2* self = (const float2*)(hs + (size_t)node * NF);
    float2 acc = self[lane];

    int base = rowptr[node];
    int cnt  = rowptr[node + 1] - base;

    for (int off = 0; off < cnt; off += 64) {
        int m = min(64, cnt - off);
        int idx = 0;
        if (lane < m) idx = csr[base + off + lane];
        int j = 0;
        for (; j + 3 < m; j += 4) {   // 4 gathers in flight
            int s0 = __shfl(idx, j, 64);
            int s1 = __shfl(idx, j + 1, 64);
            int s2 = __shfl(idx, j + 2, 64);
            int s3 = __shfl(idx, j + 3, 64);
            float2 v0 = ((const float2*)(hs + (size_t)s0 * NF))[lane];
            float2 v1 = ((const float2*)(hs + (size_t)s1 * NF))[lane];
            float2 v2 = ((const float2*)(hs + (size_t)s2 * NF))[lane];
            float2 v3 = ((const float2*)(hs + (size_t)s3 * NF))[lane];
            acc.x += v0.x + v1.x + v2.x + v3.x;
            acc.y += v0.y + v1.y + v2.y + v3.y;
        }
        for (; j < m; j++) {
            int s0 = __shfl(idx, j, 64);
            float2 v0 = ((const float2*)(hs + (size_t)s0 * NF))[lane];
            acc.x += v0.x; acc.y += v0.y;
        }
    }

    float s = dinv[node];
    float ox = s * acc.x + bias[2 * lane];
    float oy = s * acc.y + bias[2 * lane + 1];
    if (do_relu) { ox = fmaxf(ox, 0.f); oy = fmaxf(oy, 0.f); }
    ((float2*)(out + (size_t)node * NF))[lane] = make_float2(ox, oy);
}

// ---------------- launch ----------------

extern "C" void kernel_launch(void* const* d_in, const int* in_sizes, int n_in,
                              void* d_out, int out_size, void* d_ws, size_t ws_size,
                              hipStream_t stream) {
    const float* x  = (const float*)d_in[0];
    const int*   ei = (const int*)d_in[1];
    const float* W1 = (const float*)d_in[2];
    const float* b1 = (const float*)d_in[3];
    const float* W2 = (const float*)d_in[4];
    const float* b2 = (const float*)d_in[5];
    float* out = (float*)d_out;

    const int N = in_sizes[0] / NF;   // 50000
    const int E = in_sizes[1] / 2;    // 800000
    const int* src = ei;
    const int* dst = ei + E;

    char* ws = (char*)d_ws;
    size_t off = 0;
    auto alloc = [&](size_t bytes) {
        void* p = ws + off;
        off += bytes;
        off = (off + 63) & ~(size_t)63;
        return p;
    };
    int*   cnt    = (int*)alloc((size_t)N * 4);        // reused as fill cursor
    int*   rowptr = (int*)alloc((size_t)(N + 1) * 4);
    int*   csr    = (int*)alloc((size_t)E * 4);
    float* dinv   = (float*)alloc((size_t)N * 4);
    int*   bsum   = (int*)alloc((size_t)256 * 4);
    float* H      = (float*)alloc((size_t)N * NF * 4);
    float* A      = (float*)alloc((size_t)N * NF * 4);

    int nb = (N + 255) / 256;     // 196 blocks (<= 256, required by scan_blk)
    int eb = (E + 255) / 256;

    zero_int<<<nb, 256, 0, stream>>>(cnt, N);
    count_k<<<eb, 256, 0, stream>>>(dst, cnt, E, N);
    pscan_local<<<nb, 256, 0, stream>>>(cnt, dinv, rowptr, bsum, N);
    scan_blk<<<1, 256, 0, stream>>>(bsum, nb);
    add_off<<<nb, 256, 0, stream>>>(rowptr, cnt, bsum, N, E);
    fill_k<<<eb, 256, 0, stream>>>(src, dst, cnt, csr, E, N);

    dim3 gg((N + 31) / 32, 2);
    gemm_scaled<<<gg, 256, 0, stream>>>(x, W1, dinv, H, N);
    int ab = (N + 3) / 4;
    agg_k<<<ab, 256, 0, stream>>>(H, rowptr, csr, dinv, b1, A, N, 1);
    gemm_scaled<<<gg, 256, 0, stream>>>(A, W2, dinv, H, N);
    agg_k<<<ab, 256, 0, stream>>>(H, rowptr, csr, dinv, b2, out, N, 0);
}

// Round 3
// 291.440 us; speedup vs baseline: 1.4467x; 1.2285x over previous
//
#include <hip/hip_runtime.h>
#include <hip/hip_fp16.h>

#define NF 128   // feature dim, fixed by the problem

// ---------------- CSR build ----------------

__global__ void zero_int(int* __restrict__ p, int n) {
    int i = blockIdx.x * 256 + threadIdx.x;
    if (i < n) p[i] = 0;
}

__global__ void count_k(const int* __restrict__ dst, int* __restrict__ cnt, int E, int N) {
    int e = blockIdx.x * 256 + threadIdx.x;
    if (e < E) {
        int d = dst[e];
        if ((unsigned)d < (unsigned)N) atomicAdd(&cnt[d], 1);
    }
}

// Phase 1: per-256-chunk local exclusive scan (into rowptr) + block totals.
// Also computes dinv = rsqrt(deg+1) since cnt is already in hand.
__global__ __launch_bounds__(256) void pscan_local(
    const int* __restrict__ cnt, float* __restrict__ dinv,
    int* __restrict__ rowptr, int* __restrict__ blocksum, int n)
{
    __shared__ int sm[256];
    int tid = threadIdx.x;
    int i = blockIdx.x * 256 + tid;
    int v = (i < n) ? cnt[i] : 0;
    if (i < n) dinv[i] = rsqrtf((float)v + 1.0f);  // +1 = self-loop
    sm[tid] = v;
    __syncthreads();
    #pragma unroll
    for (int d = 1; d < 256; d <<= 1) {
        int t = (tid >= d) ? sm[tid - d] : 0;
        __syncthreads();
        sm[tid] += t;
        __syncthreads();
    }
    if (i < n) rowptr[i] = sm[tid] - v;            // local exclusive prefix
    if (tid == 255) blocksum[blockIdx.x] = sm[255];
}

// Phase 2: single-block exclusive scan of the block sums (nb <= 256).
__global__ __launch_bounds__(256) void scan_blk(int* __restrict__ blocksum, int nb) {
    __shared__ int sm[256];
    int tid = threadIdx.x;
    int v = (tid < nb) ? blocksum[tid] : 0;
    sm[tid] = v;
    __syncthreads();
    #pragma unroll
    for (int d = 1; d < 256; d <<= 1) {
        int t = (tid >= d) ? sm[tid - d] : 0;
        __syncthreads();
        sm[tid] += t;
        __syncthreads();
    }
    if (tid < nb) blocksum[tid] = sm[tid] - v;     // exclusive block offsets
}

// Phase 3: add block offsets; also init the fill cursor and rowptr[n].
__global__ __launch_bounds__(256) void add_off(
    int* __restrict__ rowptr, int* __restrict__ cur,
    const int* __restrict__ blocksum, int n, int E)
{
    int i = blockIdx.x * 256 + threadIdx.x;
    if (i < n) {
        int r = rowptr[i] + blocksum[blockIdx.x];
        rowptr[i] = r;
        cur[i] = r;
    }
    if (i == 0) rowptr[n] = E;   // all dst are in-range by construction
}

// XCD-partitioned fill: blockIdx&7 selects a dst-range (maps ~1:1 to an XCD
// by the usual round-robin blockIdx->XCD assignment), blockIdx>>3 selects the
// edge chunk. Each XCD then dirties only its own slice of csr -> one writeback
// per line instead of 8 partial dirty copies. The 8 sibling blocks per chunk
// are dispatch-adjacent so src/dst lines are read ~concurrently (cache reuse).
// Pure locality heuristic: correctness does not depend on the XCD mapping.
__global__ void fill_k(const int* __restrict__ src, const int* __restrict__ dst,
                       int* __restrict__ cur, int* __restrict__ csr, int E, int N) {
    int part  = blockIdx.x & 7;
    int chunk = blockIdx.x >> 3;
    int e = chunk * 256 + threadIdx.x;
    int lo = (int)(((long long)part * N) >> 3);
    int hi = (int)(((long long)(part + 1) * N) >> 3);
    if (e < E) {
        int d = dst[e];
        if (d >= lo && d < hi) {
            int p = atomicAdd(&cur[d], 1);
            csr[p] = src[e];
        }
    }
}

// ---------------- GEMM: H16[i][j] = half( dinv[i] * sum_k X[i][k] W[k][j] ) ----
// M x 128 @ 128 x 128, fp32 vector ALU, fp16 output (gather payload).
// Tile 32 rows x 64 cols, 256 threads, micro-tile 2x4. xs stride 132 -> no conflicts.

__global__ __launch_bounds__(256) void gemm_scaled(
    const float* __restrict__ X, const float* __restrict__ W,
    const float* __restrict__ dinv, __half* __restrict__ out, int M)
{
    __shared__ float xs[32][132];    // 16.9 KB
    __shared__ float ws[128][64];    // 32 KB
    const int tid  = threadIdx.x;
    const int row0 = blockIdx.x * 32;
    const int col0 = blockIdx.y * 64;

    {   // load x tile (guarded rows)
        int r = tid >> 5, c4 = (tid & 31) * 4;
        #pragma unroll
        for (int rr = r; rr < 32; rr += 8) {
            int grow = row0 + rr;
            float4 v = make_float4(0.f, 0.f, 0.f, 0.f);
            if (grow < M) v = *(const float4*)(X + (size_t)grow * NF + c4);
            *(float4*)&xs[rr][c4] = v;
        }
    }
    {   // load W half-tile (cols col0..col0+63)
        int r = tid >> 4, c4 = (tid & 15) * 4;
        #pragma unroll
        for (int rr = r; rr < 128; rr += 16) {
            float4 v = *(const float4*)(W + (size_t)rr * NF + col0 + c4);
            *(float4*)&ws[rr][c4] = v;
        }
    }
    __syncthreads();

    const int r0 = (tid >> 4) * 2;
    const int c0 = (tid & 15) * 4;
    float acc00 = 0, acc01 = 0, acc02 = 0, acc03 = 0;
    float acc10 = 0, acc11 = 0, acc12 = 0, acc13 = 0;
    #pragma unroll 8
    for (int k = 0; k < 128; k++) {
        float a0 = xs[r0][k], a1 = xs[r0 + 1][k];
        float4 b = *(const float4*)&ws[k][c0];
        acc00 += a0 * b.x; acc01 += a0 * b.y; acc02 += a0 * b.z; acc03 += a0 * b.w;
        acc10 += a1 * b.x; acc11 += a1 * b.y; acc12 += a1 * b.z; acc13 += a1 * b.w;
    }
    int g0 = row0 + r0;
    if (g0 < M) {
        float s = dinv[g0];
        float2 pack;
        ((__half2*)&pack)[0] = __floats2half2_rn(acc00 * s, acc01 * s);
        ((__half2*)&pack)[1] = __floats2half2_rn(acc02 * s, acc03 * s);
        *(float2*)(out + (size_t)g0 * NF + col0 + c0) = pack;   // 8B store
    }
    int g1 = g0 + 1;
    if (g1 < M) {
        float s = dinv[g1];
        float2 pack;
        ((__half2*)&pack)[0] = __floats2half2_rn(acc10 * s, acc11 * s);
        ((__half2*)&pack)[1] = __floats2half2_rn(acc12 * s, acc13 * s);
        *(float2*)(out + (size_t)g1 * NF + col0 + c0) = pack;
    }
}

// ---------------- Aggregation: one wave per node, fp16 gather, fp32 accumulate --
// acc = hs[node] (self-loop) + sum over in-edges hs[src];
// out = dinv[node]*acc + bias  (optional relu). Lane holds a half2 (128/64).

__global__ __launch_bounds__(256) void agg_k(
    const __half2* __restrict__ hs, const int* __restrict__ rowptr,
    const int* __restrict__ csr, const float* __restrict__ dinv,
    const float* __restrict__ bias, float* __restrict__ out,
    int n, int do_relu)
{
    int wave = threadIdx.x >> 6;
    int lane = threadIdx.x & 63;
    int node = blockIdx.x * 4 + wave;
    if (node >= n) return;

    const int HS = NF / 2;   // 64 half2 per row
    float2 acc = __half22float2(hs[(size_t)node * HS + lane]);

    int base = rowptr[node];
    int cnt  = rowptr[node + 1] - base;

    for (int off = 0; off < cnt; off += 64) {
        int m = min(64, cnt - off);
        int idx = 0;
        if (lane < m) idx = csr[base + off + lane];
        int j = 0;
        for (; j + 3 < m; j += 4) {   // 4 gathers in flight
            int s0 = __shfl(idx, j, 64);
            int s1 = __shfl(idx, j + 1, 64);
            int s2 = __shfl(idx, j + 2, 64);
            int s3 = __shfl(idx, j + 3, 64);
            __half2 v0 = hs[(size_t)s0 * HS + lane];
            __half2 v1 = hs[(size_t)s1 * HS + lane];
            __half2 v2 = hs[(size_t)s2 * HS + lane];
            __half2 v3 = hs[(size_t)s3 * HS + lane];
            float2 f0 = __half22float2(v0);
            float2 f1 = __half22float2(v1);
            float2 f2 = __half22float2(v2);
            float2 f3 = __half22float2(v3);
            acc.x += f0.x + f1.x + f2.x + f3.x;
            acc.y += f0.y + f1.y + f2.y + f3.y;
        }
        for (; j < m; j++) {
            int s0 = __shfl(idx, j, 64);
            float2 f0 = __half22float2(hs[(size_t)s0 * HS + lane]);
            acc.x += f0.x; acc.y += f0.y;
        }
    }

    float s = dinv[node];
    float ox = s * acc.x + bias[2 * lane];
    float oy = s * acc.y + bias[2 * lane + 1];
    if (do_relu) { ox = fmaxf(ox, 0.f); oy = fmaxf(oy, 0.f); }
    ((float2*)(out + (size_t)node * NF))[lane] = make_float2(ox, oy);
}

// ---------------- launch ----------------

extern "C" void kernel_launch(void* const* d_in, const int* in_sizes, int n_in,
                              void* d_out, int out_size, void* d_ws, size_t ws_size,
                              hipStream_t stream) {
    const float* x  = (const float*)d_in[0];
    const int*   ei = (const int*)d_in[1];
    const float* W1 = (const float*)d_in[2];
    const float* b1 = (const float*)d_in[3];
    const float* W2 = (const float*)d_in[4];
    const float* b2 = (const float*)d_in[5];
    float* out = (float*)d_out;

    const int N = in_sizes[0] / NF;   // 50000
    const int E = in_sizes[1] / 2;    // 800000
    const int* src = ei;
    const int* dst = ei + E;

    char* ws = (char*)d_ws;
    size_t off = 0;
    auto alloc = [&](size_t bytes) {
        void* p = ws + off;
        off += bytes;
        off = (off + 63) & ~(size_t)63;
        return p;
    };
    int*    cnt    = (int*)alloc((size_t)N * 4);        // reused as fill cursor
    int*    rowptr = (int*)alloc((size_t)(N + 1) * 4);
    int*    csr    = (int*)alloc((size_t)E * 4);
    float*  dinv   = (float*)alloc((size_t)N * 4);
    int*    bsum   = (int*)alloc((size_t)256 * 4);
    __half* H16    = (__half*)alloc((size_t)N * NF * 2);
    float*  A      = (float*)alloc((size_t)N * NF * 4);

    int nb = (N + 255) / 256;     // 196 blocks (<= 256, required by scan_blk)
    int eb = (E + 255) / 256;

    zero_int<<<nb, 256, 0, stream>>>(cnt, N);
    count_k<<<eb, 256, 0, stream>>>(dst, cnt, E, N);
    pscan_local<<<nb, 256, 0, stream>>>(cnt, dinv, rowptr, bsum, N);
    scan_blk<<<1, 256, 0, stream>>>(bsum, nb);
    add_off<<<nb, 256, 0, stream>>>(rowptr, cnt, bsum, N, E);
    fill_k<<<eb * 8, 256, 0, stream>>>(src, dst, cnt, csr, E, N);

    dim3 gg((N + 31) / 32, 2);
    gemm_scaled<<<gg, 256, 0, stream>>>(x, W1, dinv, H16, N);
    int ab = (N + 3) / 4;
    agg_k<<<ab, 256, 0, stream>>>((const __half2*)H16, rowptr, csr, dinv, b1, A, N, 1);
    gemm_scaled<<<gg, 256, 0, stream>>>(A, W2, dinv, H16, N);
    agg_k<<<ab, 256, 0, stream>>>((const __half2*)H16, rowptr, csr, dinv, b2, out, N, 0);
}

// Round 5
// 255.665 us; speedup vs baseline: 1.6491x; 1.1399x over previous
//
#include <hip/hip_runtime.h>
#include <hip/hip_fp16.h>

#define NF 128   // feature dim, fixed by the problem

typedef _Float16 half8 __attribute__((ext_vector_type(8)));
typedef float    floatx4 __attribute__((ext_vector_type(4)));

// ---------------- CSR build ----------------

__global__ void zero_int(int* __restrict__ p, int n) {
    int i = blockIdx.x * 256 + threadIdx.x;
    if (i < n) p[i] = 0;
}

__global__ void count_k(const int* __restrict__ dst, int* __restrict__ cnt, int E, int N) {
    int e = blockIdx.x * 256 + threadIdx.x;
    if (e < E) {
        int d = dst[e];
        if ((unsigned)d < (unsigned)N) atomicAdd(&cnt[d], 1);
    }
}

// Phase 1: per-256-chunk local exclusive scan (into rowptr) + block totals.
// Also computes dinv = rsqrt(deg+1) since cnt is already in hand.
__global__ __launch_bounds__(256) void pscan_local(
    const int* __restrict__ cnt, float* __restrict__ dinv,
    int* __restrict__ rowptr, int* __restrict__ blocksum, int n)
{
    __shared__ int sm[256];
    int tid = threadIdx.x;
    int i = blockIdx.x * 256 + tid;
    int v = (i < n) ? cnt[i] : 0;
    if (i < n) dinv[i] = rsqrtf((float)v + 1.0f);  // +1 = self-loop
    sm[tid] = v;
    __syncthreads();
    #pragma unroll
    for (int d = 1; d < 256; d <<= 1) {
        int t = (tid >= d) ? sm[tid - d] : 0;
        __syncthreads();
        sm[tid] += t;
        __syncthreads();
    }
    if (i < n) rowptr[i] = sm[tid] - v;            // local exclusive prefix
    if (tid == 255) blocksum[blockIdx.x] = sm[255];
}

// Phase 2: single-block exclusive scan of the block sums (nb <= 256).
__global__ __launch_bounds__(256) void scan_blk(int* __restrict__ blocksum, int nb) {
    __shared__ int sm[256];
    int tid = threadIdx.x;
    int v = (tid < nb) ? blocksum[tid] : 0;
    sm[tid] = v;
    __syncthreads();
    #pragma unroll
    for (int d = 1; d < 256; d <<= 1) {
        int t = (tid >= d) ? sm[tid - d] : 0;
        __syncthreads();
        sm[tid] += t;
        __syncthreads();
    }
    if (tid < nb) blocksum[tid] = sm[tid] - v;     // exclusive block offsets
}

// Phase 3: add block offsets; also init the fill cursor and rowptr[n].
__global__ __launch_bounds__(256) void add_off(
    int* __restrict__ rowptr, int* __restrict__ cur,
    const int* __restrict__ blocksum, int n, int E)
{
    int i = blockIdx.x * 256 + threadIdx.x;
    if (i < n) {
        int r = rowptr[i] + blocksum[blockIdx.x];
        rowptr[i] = r;
        cur[i] = r;
    }
    if (i == 0) rowptr[n] = E;   // all dst are in-range by construction
}

// XCD-partitioned fill (see R2 note): blockIdx&7 selects a dst-range so each
// XCD dirties only its own slice of csr -> one writeback per line.
__global__ void fill_k(const int* __restrict__ src, const int* __restrict__ dst,
                       int* __restrict__ cur, int* __restrict__ csr, int E, int N) {
    int part  = blockIdx.x & 7;
    int chunk = blockIdx.x >> 3;
    int e = chunk * 256 + threadIdx.x;
    int lo = (int)(((long long)part * N) >> 3);
    int hi = (int)(((long long)(part + 1) * N) >> 3);
    if (e < E) {
        int d = dst[e];
        if (d >= lo && d < hi) {
            int p = atomicAdd(&cur[d], 1);
            csr[p] = src[e];
        }
    }
}

// ---------------- W transpose+fp16: WT[n][k] = half(W[k][n]) ----------------
__global__ void convW_k(const float* __restrict__ W1, const float* __restrict__ W2,
                        __half* __restrict__ WT1, __half* __restrict__ WT2) {
    int idx = blockIdx.x * 256 + threadIdx.x;   // 0..16383
    const float* W  = (blockIdx.y == 0) ? W1 : W2;
    __half* WT      = (blockIdx.y == 0) ? WT1 : WT2;
    int n = idx & 127, k = idx >> 7;
    WT[n * NF + k] = __float2half(W[k * NF + n]);
}

// ---------------- MFMA GEMM: out16[i][j] = half( dinv[i] * sum_k X[i][k] W[k][j] )
// 256 thr = 4 waves; 64 rows/block, full 128 cols per wave. K=128 via 4 chunks of 32.
// mfma_f32_16x16x32_f16 layouts: A[m=lane&15][k=quad*8+j]; B[k=quad*8+j][n=lane&15];
// D: row=quad*4+reg, col=lane&15 (m89/m91, dtype-independent).

template<bool F32IN>
__global__ __launch_bounds__(256) void mfma_gemm(
    const void* __restrict__ Xv, const __half* __restrict__ WT,
    const float* __restrict__ dinv, __half* __restrict__ out, int M)
{
    __shared__ __half wlds[128][136];   // pitch 272B: 16B-aligned, <=2-way banks
    const int tid = threadIdx.x;

    {   // stage WT (128x128 halves): 2 threads/row, 64 halves (8 x half8) each
        int r = tid >> 1;
        int c0 = (tid & 1) * 64;
        const half8* s = (const half8*)(WT + (size_t)r * NF + c0);
        half8* d = (half8*)&wlds[r][c0];
        #pragma unroll
        for (int j = 0; j < 8; j++) d[j] = s[j];   // R4 bugfix: was only 4 (half the tile!)
    }
    __syncthreads();

    const int wave = tid >> 6, lane = tid & 63;
    const int quad = lane >> 4, l15 = lane & 15;
    const int rowA = blockIdx.x * 64 + wave * 16 + l15;
    const int rowc = (rowA < M) ? rowA : (M - 1);   // clamp (dup row, never stored)

    half8 afr[4];
    if (F32IN) {
        const float* X = (const float*)Xv;
        #pragma unroll
        for (int kc = 0; kc < 4; kc++) {
            const floatx4* p = (const floatx4*)(X + (size_t)rowc * NF + kc * 32 + quad * 8);
            floatx4 u = p[0], v = p[1];
            half8 a;
            a[0] = (_Float16)u[0]; a[1] = (_Float16)u[1];
            a[2] = (_Float16)u[2]; a[3] = (_Float16)u[3];
            a[4] = (_Float16)v[0]; a[5] = (_Float16)v[1];
            a[6] = (_Float16)v[2]; a[7] = (_Float16)v[3];
            afr[kc] = a;
        }
    } else {
        const __half* X = (const __half*)Xv;
        #pragma unroll
        for (int kc = 0; kc < 4; kc++)
            afr[kc] = *(const half8*)(X + (size_t)rowc * NF + kc * 32 + quad * 8);
    }

    floatx4 acc[8];
    #pragma unroll
    for (int ct = 0; ct < 8; ct++) { floatx4 z = {0.f, 0.f, 0.f, 0.f}; acc[ct] = z; }

    #pragma unroll
    for (int kc = 0; kc < 4; kc++) {
        #pragma unroll
        for (int ct = 0; ct < 8; ct++) {
            half8 b = *(const half8*)&wlds[ct * 16 + l15][kc * 32 + quad * 8];
            acc[ct] = __builtin_amdgcn_mfma_f32_16x16x32_f16(afr[kc], b, acc[ct], 0, 0, 0);
        }
    }

    const int orow0 = blockIdx.x * 64 + wave * 16 + quad * 4;
    #pragma unroll
    for (int r = 0; r < 4; r++) {
        int orow = orow0 + r;
        if (orow < M) {
            float s = dinv[orow];
            #pragma unroll
            for (int ct = 0; ct < 8; ct++)
                out[(size_t)orow * NF + ct * 16 + l15] = __float2half(acc[ct][r] * s);
        }
    }
}

// ---------------- Aggregation: one wave per node, fp16 gather, fp32 accumulate --
// acc = hs[node] + sum_{e in(node)} hs[src_e];  res = dinv[node]*acc + bias.
// outh != null: write half(relu(res)) (layer-1 path); else write float res.

__global__ __launch_bounds__(256) void agg_k(
    const __half2* __restrict__ hs, const int* __restrict__ rowptr,
    const int* __restrict__ csr, const float* __restrict__ dinv,
    const float* __restrict__ bias, __half2* __restrict__ outh,
    float* __restrict__ outf, int n)
{
    int wave = threadIdx.x >> 6;
    int lane = threadIdx.x & 63;
    int node = blockIdx.x * 4 + wave;
    if (node >= n) return;

    const int HS = NF / 2;   // 64 half2 per row
    float2 acc = __half22float2(hs[(size_t)node * HS + lane]);

    int base = rowptr[node];
    int cnt  = rowptr[node + 1] - base;

    for (int off = 0; off < cnt; off += 64) {
        int m = min(64, cnt - off);
        int idx = 0;
        if (lane < m) idx = csr[base + off + lane];
        int j = 0;
        for (; j + 7 < m; j += 8) {   // 8 gathers in flight
            int s0 = __shfl(idx, j, 64);
            int s1 = __shfl(idx, j + 1, 64);
            int s2 = __shfl(idx, j + 2, 64);
            int s3 = __shfl(idx, j + 3, 64);
            int s4 = __shfl(idx, j + 4, 64);
            int s5 = __shfl(idx, j + 5, 64);
            int s6 = __shfl(idx, j + 6, 64);
            int s7 = __shfl(idx, j + 7, 64);
            __half2 v0 = hs[(size_t)s0 * HS + lane];
            __half2 v1 = hs[(size_t)s1 * HS + lane];
            __half2 v2 = hs[(size_t)s2 * HS + lane];
            __half2 v3 = hs[(size_t)s3 * HS + lane];
            __half2 v4 = hs[(size_t)s4 * HS + lane];
            __half2 v5 = hs[(size_t)s5 * HS + lane];
            __half2 v6 = hs[(size_t)s6 * HS + lane];
            __half2 v7 = hs[(size_t)s7 * HS + lane];
            float2 f0 = __half22float2(v0), f1 = __half22float2(v1);
            float2 f2 = __half22float2(v2), f3 = __half22float2(v3);
            float2 f4 = __half22float2(v4), f5 = __half22float2(v5);
            float2 f6 = __half22float2(v6), f7 = __half22float2(v7);
            acc.x += (f0.x + f1.x) + (f2.x + f3.x) + (f4.x + f5.x) + (f6.x + f7.x);
            acc.y += (f0.y + f1.y) + (f2.y + f3.y) + (f4.y + f5.y) + (f6.y + f7.y);
        }
        for (; j < m; j++) {
            int s0 = __shfl(idx, j, 64);
            float2 f0 = __half22float2(hs[(size_t)s0 * HS + lane]);
            acc.x += f0.x; acc.y += f0.y;
        }
    }

    float s = dinv[node];
    float ox = s * acc.x + bias[2 * lane];
    float oy = s * acc.y + bias[2 * lane + 1];
    if (outh) {
        ox = fmaxf(ox, 0.f); oy = fmaxf(oy, 0.f);
        outh[(size_t)node * HS + lane] = __floats2half2_rn(ox, oy);
    } else {
        ((float2*)(outf + (size_t)node * NF))[lane] = make_float2(ox, oy);
    }
}

// ---------------- launch ----------------

extern "C" void kernel_launch(void* const* d_in, const int* in_sizes, int n_in,
                              void* d_out, int out_size, void* d_ws, size_t ws_size,
                              hipStream_t stream) {
    const float* x  = (const float*)d_in[0];
    const int*   ei = (const int*)d_in[1];
    const float* W1 = (const float*)d_in[2];
    const float* b1 = (const float*)d_in[3];
    const float* W2 = (const float*)d_in[4];
    const float* b2 = (const float*)d_in[5];
    float* out = (float*)d_out;

    const int N = in_sizes[0] / NF;   // 50000
    const int E = in_sizes[1] / 2;    // 800000
    const int* src = ei;
    const int* dst = ei + E;

    char* ws = (char*)d_ws;
    size_t off = 0;
    auto alloc = [&](size_t bytes) {
        void* p = ws + off;
        off += bytes;
        off = (off + 63) & ~(size_t)63;
        return p;
    };
    int*    cnt    = (int*)alloc((size_t)N * 4);        // reused as fill cursor
    int*    rowptr = (int*)alloc((size_t)(N + 1) * 4);
    int*    csr    = (int*)alloc((size_t)E * 4);
    float*  dinv   = (float*)alloc((size_t)N * 4);
    int*    bsum   = (int*)alloc((size_t)256 * 4);
    __half* WT1    = (__half*)alloc((size_t)NF * NF * 2);
    __half* WT2    = (__half*)alloc((size_t)NF * NF * 2);
    __half* H16    = (__half*)alloc((size_t)N * NF * 2);
    __half* A16    = (__half*)alloc((size_t)N * NF * 2);

    int nb = (N + 255) / 256;     // 196 blocks (<= 256, required by scan_blk)
    int eb = (E + 255) / 256;

    zero_int<<<nb, 256, 0, stream>>>(cnt, N);
    count_k<<<eb, 256, 0, stream>>>(dst, cnt, E, N);
    pscan_local<<<nb, 256, 0, stream>>>(cnt, dinv, rowptr, bsum, N);
    scan_blk<<<1, 256, 0, stream>>>(bsum, nb);
    add_off<<<nb, 256, 0, stream>>>(rowptr, cnt, bsum, N, E);
    fill_k<<<eb * 8, 256, 0, stream>>>(src, dst, cnt, csr, E, N);
    convW_k<<<dim3(64, 2), 256, 0, stream>>>(W1, W2, WT1, WT2);

    int gb = (N + 63) / 64;
    int ab = (N + 3) / 4;
    mfma_gemm<true><<<gb, 256, 0, stream>>>(x, WT1, dinv, H16, N);
    agg_k<<<ab, 256, 0, stream>>>((const __half2*)H16, rowptr, csr, dinv, b1,
                                  (__half2*)A16, nullptr, N);
    mfma_gemm<false><<<gb, 256, 0, stream>>>(A16, WT2, dinv, H16, N);
    agg_k<<<ab, 256, 0, stream>>>((const __half2*)H16, rowptr, csr, dinv, b2,
                                  nullptr, out, N);
}